// Round 1
// baseline (493.843 us; speedup 1.0000x reference)
//
#include <hip/hip_runtime.h>
#include <math.h>

#define BN_EPS 1e-5f
#define NEG_SLOPE 0.2f

__device__ __forceinline__ float relu_f(float x) { return x > 0.f ? x : 0.f; }

// ---------------- conv1: 3->64, 3x3 SAME, 8x3x64x64, fused bias+BN+ReLU ----------------
__global__ void conv1_fused(const float* __restrict__ img,
                            const float* __restrict__ w, const float* __restrict__ cb,
                            const float* __restrict__ g, const float* __restrict__ bb,
                            const float* __restrict__ m, const float* __restrict__ vv,
                            float* __restrict__ out)
{
    int idx = blockIdx.x * blockDim.x + threadIdx.x;
    if (idx >= 8 * 64 * 64 * 64) return;
    int x = idx & 63, y = (idx >> 6) & 63, o = (idx >> 12) & 63, b = idx >> 18;
    const float* wp = w + o * 27;
    const float* ip = img + b * 3 * 4096;
    float acc = 0.f;
#pragma unroll
    for (int ky = 0; ky < 3; ++ky) {
        int yy = y + ky - 1;
        if ((unsigned)yy > 63u) continue;
#pragma unroll
        for (int kx = 0; kx < 3; ++kx) {
            int xx = x + kx - 1;
            if ((unsigned)xx > 63u) continue;
#pragma unroll
            for (int i = 0; i < 3; ++i)
                acc += ip[i * 4096 + yy * 64 + xx] * wp[i * 9 + ky * 3 + kx];
        }
    }
    float inv = g[o] / sqrtf(vv[o] + BN_EPS);
    float val = (acc + cb[o]) * inv + (bb[o] - m[o] * inv);
    out[idx] = relu_f(val);
}

// ---------------- 2x2 maxpool: 8x64x64x64 -> 8x64x32x32 ----------------
__global__ void pool2x2(const float* __restrict__ in, float* __restrict__ out)
{
    int idx = blockIdx.x * blockDim.x + threadIdx.x;
    if (idx >= 8 * 64 * 32 * 32) return;
    int x = idx & 31, y = (idx >> 5) & 31, c = (idx >> 10) & 63, b = idx >> 16;
    const float* p = in + ((b * 64 + c) * 64 + 2 * y) * 64 + 2 * x;
    out[idx] = fmaxf(fmaxf(p[0], p[1]), fmaxf(p[64], p[65]));
}

// ---------------- conv2: 64->128, 3x3 SAME, fused bias+BN+ReLU, writes node-major x0[n,128] ----------------
__global__ void conv2_fused(const float* __restrict__ in,
                            const float* __restrict__ w, const float* __restrict__ cb,
                            const float* __restrict__ g, const float* __restrict__ bb,
                            const float* __restrict__ m, const float* __restrict__ vv,
                            float* __restrict__ x0)
{
    int idx = blockIdx.x * blockDim.x + threadIdx.x;
    if (idx >= 8 * 128 * 32 * 32) return;
    int x = idx & 31, y = (idx >> 5) & 31, o = (idx >> 10) & 127, b = idx >> 17;
    const float* ip = in + b * 64 * 1024;
    const float* wp = w + o * 576;
    float acc = 0.f;
    for (int ky = 0; ky < 3; ++ky) {
        int yy = y + ky - 1;
        if ((unsigned)yy > 31u) continue;
        for (int kx = 0; kx < 3; ++kx) {
            int xx = x + kx - 1;
            if ((unsigned)xx > 31u) continue;
            const float* ipp = ip + yy * 32 + xx;
            const float* wpp = wp + ky * 3 + kx;
#pragma unroll 8
            for (int i = 0; i < 64; ++i)
                acc += ipp[i * 1024] * wpp[i * 9];
        }
    }
    float inv = g[o] / sqrtf(vv[o] + BN_EPS);
    float val = (acc + cb[o]) * inv + (bb[o] - m[o] * inv);
    int n = b * 1024 + y * 32 + x;
    x0[n * 128 + o] = relu_f(val);
}

// ---------------- naive GEMM: C[n,c] = sum_k A[n,k] B[k,c]; M = 1<<MLOG ----------------
template <int K, int MLOG>
__global__ void gemm_naive(const float* __restrict__ A, const float* __restrict__ B,
                           float* __restrict__ C, int total)
{
    int idx = blockIdx.x * blockDim.x + threadIdx.x;
    if (idx >= total) return;
    const int M = 1 << MLOG;
    int c = idx & (M - 1), n = idx >> MLOG;
    const float* a = A + (size_t)n * K;
    const float* bp = B + c;
    float acc = 0.f;
#pragma unroll 8
    for (int k = 0; k < K; ++k) acc += a[k] * bp[(size_t)k * M];
    C[idx] = acc;
}

// ---------------- per-node attention scores: s = h@a_src, d = h@a_dst (one wave per row) ----------------
__global__ void score_kernel(const float* __restrict__ h, const float* __restrict__ asrc,
                             const float* __restrict__ adst, float* __restrict__ s,
                             float* __restrict__ d, int D, int N)
{
    int gt = blockIdx.x * blockDim.x + threadIdx.x;
    int wave = gt >> 6, lane = gt & 63;
    if (wave >= N) return;
    const float* hp = h + (size_t)wave * D;
    float ss = 0.f, dd = 0.f;
    for (int c = lane; c < D; c += 64) {
        float hv = hp[c];
        ss += hv * asrc[c];
        dd += hv * adst[c];
    }
    for (int off = 32; off; off >>= 1) {
        ss += __shfl_down(ss, off);
        dd += __shfl_down(dd, off);
    }
    if (lane == 0) { s[wave] = ss; d[wave] = dd; }
}

// ---------------- dense GAT aggregation for dst v in [0,1024): softmax over all u in [0,1024) ----------------
template <int D>
__global__ void gat_agg(const float* __restrict__ h, const float* __restrict__ s,
                        const float* __restrict__ dsc, const float* __restrict__ bias,
                        float* __restrict__ out)
{
    __shared__ float alpha[1024];
    __shared__ float red[D];
    const int UPT = 1024 / D;
    int v = blockIdx.x, t = threadIdx.x;
    float dv = dsc[v];
    float e[UPT];
    float lmax = -1e30f;
#pragma unroll
    for (int j = 0; j < UPT; ++j) {
        float xx = s[t + j * D] + dv;
        xx = xx > 0.f ? xx : NEG_SLOPE * xx;   // leaky_relu
        e[j] = xx;
        lmax = fmaxf(lmax, xx);
    }
    red[t] = lmax;
    __syncthreads();
    for (int off = D / 2; off; off >>= 1) {
        if (t < off) red[t] = fmaxf(red[t], red[t + off]);
        __syncthreads();
    }
    float gmax = red[0];
    __syncthreads();
    float lsum = 0.f;
#pragma unroll
    for (int j = 0; j < UPT; ++j) {
        float ex = expf(e[j] - gmax);
        alpha[t + j * D] = ex;
        lsum += ex;
    }
    red[t] = lsum;
    __syncthreads();
    for (int off = D / 2; off; off >>= 1) {
        if (t < off) red[t] += red[t + off];
        __syncthreads();
    }
    float denom = red[0];
    float acc = 0.f;
#pragma unroll 8
    for (int u = 0; u < 1024; ++u)
        acc += alpha[u] * h[u * D + t];
    out[v * D + t] = relu_f(acc / denom + bias[t]);
}

// ---------------- self-loop-only rows v in [1024,8192): out = relu(h[v] + bias) ----------------
__global__ void gat_self(const float* __restrict__ h, const float* __restrict__ bias,
                         float* __restrict__ out, int DLOG)
{
    int idx = blockIdx.x * blockDim.x + threadIdx.x;
    int D = 1 << DLOG;
    int total = 7168 << DLOG;
    if (idx >= total) return;
    int c = idx & (D - 1);
    int n = 1024 + (idx >> DLOG);
    size_t off = ((size_t)n << DLOG) + c;
    out[off] = relu_f(h[off] + bias[c]);
}

// ---------------- mean-pool per image + final linear + log_softmax ----------------
__global__ void head_kernel(const float* __restrict__ x2, const float* __restrict__ ow,
                            const float* __restrict__ ob, float* __restrict__ out)
{
    __shared__ float pooled[128];
    __shared__ float logits[10];
    int b = blockIdx.x;   // 0..7
    int t = threadIdx.x;  // 0..127
    const float* p = x2 + (size_t)b * 1024 * 128;
    float acc = 0.f;
    for (int n = 0; n < 1024; ++n) acc += p[n * 128 + t];
    pooled[t] = acc * (1.f / 1024.f);
    __syncthreads();
    if (t < 10) {
        float l = ob[t];
        for (int c = 0; c < 128; ++c) l += pooled[c] * ow[c * 10 + t];
        logits[t] = l;
    }
    __syncthreads();
    if (t == 0) {
        float mx = logits[0];
        for (int j = 1; j < 10; ++j) mx = fmaxf(mx, logits[j]);
        float sum = 0.f;
        for (int j = 0; j < 10; ++j) sum += expf(logits[j] - mx);
        float lse = mx + logf(sum);
        for (int j = 0; j < 10; ++j) out[b * 10 + j] = logits[j] - lse;
    }
}

extern "C" void kernel_launch(void* const* d_in, const int* in_sizes, int n_in,
                              void* d_out, int out_size, void* d_ws, size_t ws_size,
                              hipStream_t stream)
{
    const float* images = (const float*)d_in[0];
    const float* c1w = (const float*)d_in[1];
    const float* c1b = (const float*)d_in[2];
    const float* bn1g = (const float*)d_in[3];
    const float* bn1b = (const float*)d_in[4];
    const float* bn1m = (const float*)d_in[5];
    const float* bn1v = (const float*)d_in[6];
    const float* c2w = (const float*)d_in[7];
    const float* c2b = (const float*)d_in[8];
    const float* bn2g = (const float*)d_in[9];
    const float* bn2b = (const float*)d_in[10];
    const float* bn2m = (const float*)d_in[11];
    const float* bn2v = (const float*)d_in[12];
    const float* g1w = (const float*)d_in[13];
    const float* g1as = (const float*)d_in[14];
    const float* g1ad = (const float*)d_in[15];
    const float* g1b = (const float*)d_in[16];
    const float* g2w = (const float*)d_in[17];
    const float* g2as = (const float*)d_in[18];
    const float* g2ad = (const float*)d_in[19];
    const float* g2b = (const float*)d_in[20];
    const float* ow = (const float*)d_in[21];
    const float* ob = (const float*)d_in[22];
    float* out = (float*)d_out;

    // workspace layout (floats); x1 aliases buf1 (dead after pool), x2 aliases x0 (dead after gemm1)
    float* ws = (float*)d_ws;
    float* buf1 = ws;               // 2,097,152 : conv1 out  (later x1 [8192,256])
    float* buf2 = ws + 2097152;     //   524,288 : pool out
    float* x0   = ws + 2621440;     // 1,048,576 : node feats [8192,128] (later x2)
    float* h1   = ws + 3670016;     // 2,097,152 : [8192,256]
    float* s1   = ws + 5767168;     //     8,192
    float* d1   = ws + 5775360;     //     8,192
    float* h2   = ws + 5783552;     // 1,048,576 : [8192,128]
    float* s2   = ws + 6832128;     //     8,192
    float* d2   = ws + 6840320;     //     8,192
    float* x1 = buf1;
    float* x2 = x0;

    conv1_fused<<<8192, 256, 0, stream>>>(images, c1w, c1b, bn1g, bn1b, bn1m, bn1v, buf1);
    pool2x2<<<2048, 256, 0, stream>>>(buf1, buf2);
    conv2_fused<<<4096, 256, 0, stream>>>(buf2, c2w, c2b, bn2g, bn2b, bn2m, bn2v, x0);

    gemm_naive<128, 8><<<8192, 256, 0, stream>>>(x0, g1w, h1, 8192 * 256);
    score_kernel<<<2048, 256, 0, stream>>>(h1, g1as, g1ad, s1, d1, 256, 8192);
    gat_agg<256><<<1024, 256, 0, stream>>>(h1, s1, d1, g1b, x1);
    gat_self<<<7168, 256, 0, stream>>>(h1, g1b, x1, 8);

    gemm_naive<256, 7><<<4096, 256, 0, stream>>>(x1, g2w, h2, 8192 * 128);
    score_kernel<<<2048, 256, 0, stream>>>(h2, g2as, g2ad, s2, d2, 128, 8192);
    gat_agg<128><<<1024, 128, 0, stream>>>(h2, s2, d2, g2b, x2);
    gat_self<<<3584, 256, 0, stream>>>(h2, g2b, x2, 7);

    head_kernel<<<8, 128, 0, stream>>>(x2, ow, ob, out);
}

// Round 2
// 356.667 us; speedup vs baseline: 1.3846x; 1.3846x over previous
//
#include <hip/hip_runtime.h>
#include <math.h>

#define BN_EPS 1e-5f
#define NEG_SLOPE 0.2f

__device__ __forceinline__ float relu_f(float x) { return x > 0.f ? x : 0.f; }

// ---------------- conv1: 3->64, 3x3 SAME, 8x3x64x64, fused bias+BN+ReLU ----------------
__global__ void conv1_fused(const float* __restrict__ img,
                            const float* __restrict__ w, const float* __restrict__ cb,
                            const float* __restrict__ g, const float* __restrict__ bb,
                            const float* __restrict__ m, const float* __restrict__ vv,
                            float* __restrict__ out)
{
    int idx = blockIdx.x * blockDim.x + threadIdx.x;
    if (idx >= 8 * 64 * 64 * 64) return;
    int x = idx & 63, y = (idx >> 6) & 63, o = (idx >> 12) & 63, b = idx >> 18;
    const float* wp = w + o * 27;
    const float* ip = img + b * 3 * 4096;
    float acc = 0.f;
#pragma unroll
    for (int ky = 0; ky < 3; ++ky) {
        int yy = y + ky - 1;
        if ((unsigned)yy > 63u) continue;
#pragma unroll
        for (int kx = 0; kx < 3; ++kx) {
            int xx = x + kx - 1;
            if ((unsigned)xx > 63u) continue;
#pragma unroll
            for (int i = 0; i < 3; ++i)
                acc += ip[i * 4096 + yy * 64 + xx] * wp[i * 9 + ky * 3 + kx];
        }
    }
    float inv = g[o] / sqrtf(vv[o] + BN_EPS);
    float val = (acc + cb[o]) * inv + (bb[o] - m[o] * inv);
    out[idx] = relu_f(val);
}

// ---------------- 2x2 maxpool: 8x64x64x64 -> 8x64x32x32 ----------------
__global__ void pool2x2(const float* __restrict__ in, float* __restrict__ out)
{
    int idx = blockIdx.x * blockDim.x + threadIdx.x;
    if (idx >= 8 * 64 * 32 * 32) return;
    int x = idx & 31, y = (idx >> 5) & 31, c = (idx >> 10) & 63, b = idx >> 16;
    const float* p = in + ((b * 64 + c) * 64 + 2 * y) * 64 + 2 * x;
    out[idx] = fmaxf(fmaxf(p[0], p[1]), fmaxf(p[64], p[65]));
}

// ---------------- conv2: 64->128, 3x3 SAME. Register-blocked: 8 co per thread. ----------------
// grid: img(8) x cog(16) x quarter(4) = 512 blocks, 256 threads (one spatial pos each)
__global__ void conv2_fused(const float* __restrict__ in,
                            const float* __restrict__ w, const float* __restrict__ cb,
                            const float* __restrict__ g, const float* __restrict__ bb,
                            const float* __restrict__ m, const float* __restrict__ vv,
                            float* __restrict__ x0)
{
    int blk = blockIdx.x;
    int q = blk & 3;            // rows q*8 .. q*8+7
    int cog = (blk >> 2) & 15;  // 8 output channels per group
    int b = blk >> 6;           // image
    int t = threadIdx.x;
    int x = t & 31, y = (q << 3) + (t >> 5);

    const float* ip = in + b * 64 * 1024 + y * 32 + x;
    const float* wp = w + cog * 8 * 576;

    float acc[8] = {0.f, 0.f, 0.f, 0.f, 0.f, 0.f, 0.f, 0.f};

    for (int ci = 0; ci < 64; ++ci) {
        const float* base = ip + ci * 1024;
        float r[9];
#pragma unroll
        for (int ky = 0; ky < 3; ++ky) {
            int yy = y + ky - 1;
            bool yok = (unsigned)yy <= 31u;
#pragma unroll
            for (int kx = 0; kx < 3; ++kx) {
                int xx = x + kx - 1;
                bool ok = yok && ((unsigned)xx <= 31u);
                r[ky * 3 + kx] = ok ? base[(ky - 1) * 32 + (kx - 1)] : 0.f;
            }
        }
        const float* wc = wp + ci * 9;
#pragma unroll
        for (int j = 0; j < 8; ++j) {
            const float* wj = wc + j * 576;
#pragma unroll
            for (int k = 0; k < 9; ++k)
                acc[j] += r[k] * wj[k];
        }
    }

    int n = b * 1024 + y * 32 + x;
#pragma unroll
    for (int j = 0; j < 8; ++j) {
        int co = cog * 8 + j;
        float inv = g[co] / sqrtf(vv[co] + BN_EPS);
        float val = (acc[j] + cb[co]) * inv + (bb[co] - m[co] * inv);
        x0[n * 128 + co] = relu_f(val);
    }
}

// ---------------- register-blocked GEMM: C[n,c] = sum_k A[n,k] B[k,c] ----------------
// block = M threads (one per output column c), NR rows per block
template <int K, int M, int NR>
__global__ void gemm_rb(const float* __restrict__ A, const float* __restrict__ B,
                        float* __restrict__ C)
{
    int c = threadIdx.x;
    int n0 = blockIdx.x * NR;
    const float* a = A + (size_t)n0 * K;
    float acc[NR];
#pragma unroll
    for (int j = 0; j < NR; ++j) acc[j] = 0.f;

    for (int k = 0; k < K; ++k) {
        float bv = B[(size_t)k * M + c];
#pragma unroll
        for (int j = 0; j < NR; ++j)
            acc[j] += a[(size_t)j * K + k] * bv;
    }
#pragma unroll
    for (int j = 0; j < NR; ++j)
        C[(size_t)(n0 + j) * M + c] = acc[j];
}

// ---------------- per-node attention scores: s = h@a_src, d = h@a_dst (one wave per row) ----------------
__global__ void score_kernel(const float* __restrict__ h, const float* __restrict__ asrc,
                             const float* __restrict__ adst, float* __restrict__ s,
                             float* __restrict__ d, int D, int N)
{
    int gt = blockIdx.x * blockDim.x + threadIdx.x;
    int wave = gt >> 6, lane = gt & 63;
    if (wave >= N) return;
    const float* hp = h + (size_t)wave * D;
    float ss = 0.f, dd = 0.f;
    for (int c = lane; c < D; c += 64) {
        float hv = hp[c];
        ss += hv * asrc[c];
        dd += hv * adst[c];
    }
    for (int off = 32; off; off >>= 1) {
        ss += __shfl_down(ss, off);
        dd += __shfl_down(dd, off);
    }
    if (lane == 0) { s[wave] = ss; d[wave] = dd; }
}

// ---------------- dense GAT aggregation, 4 dst rows per block ----------------
// block = D threads; grid = 256 blocks (v in [0,1024))
template <int D>
__global__ void gat_agg4(const float* __restrict__ h, const float* __restrict__ s,
                         const float* __restrict__ dsc, const float* __restrict__ bias,
                         float* __restrict__ out)
{
    __shared__ float ss[1024];
    __shared__ float4 alpha[1024];   // alpha[u] = {exp for j=0..3}
    __shared__ float rdenom[4];
    const int NW = D / 64;
    int v0 = blockIdx.x * 4;
    int t = threadIdx.x;
    int lane = t & 63, wave = t >> 6;

    for (int u = t; u < 1024; u += D) ss[u] = s[u];
    __syncthreads();

    for (int j = wave; j < 4; j += NW) {
        float dv = dsc[v0 + j];
        float ev[16];
        float lmax = -1e30f;
#pragma unroll
        for (int k = 0; k < 16; ++k) {
            float e = ss[lane + k * 64] + dv;
            e = e > 0.f ? e : NEG_SLOPE * e;
            ev[k] = e;
            lmax = fmaxf(lmax, e);
        }
#pragma unroll
        for (int off = 1; off < 64; off <<= 1)
            lmax = fmaxf(lmax, __shfl_xor(lmax, off));
        float lsum = 0.f;
#pragma unroll
        for (int k = 0; k < 16; ++k) {
            float ex = __expf(ev[k] - lmax);
            ((float*)&alpha[lane + k * 64])[j] = ex;
            lsum += ex;
        }
#pragma unroll
        for (int off = 1; off < 64; off <<= 1)
            lsum += __shfl_xor(lsum, off);
        if (lane == 0) rdenom[j] = 1.f / lsum;
    }
    __syncthreads();

    float acc0 = 0.f, acc1 = 0.f, acc2 = 0.f, acc3 = 0.f;
    const float* hp = h + t;
    for (int u = 0; u < 1024; ++u) {
        float4 a4 = alpha[u];
        float hv = hp[(size_t)u * D];
        acc0 += a4.x * hv;
        acc1 += a4.y * hv;
        acc2 += a4.z * hv;
        acc3 += a4.w * hv;
    }
    float bi = bias[t];
    out[(size_t)(v0 + 0) * D + t] = relu_f(acc0 * rdenom[0] + bi);
    out[(size_t)(v0 + 1) * D + t] = relu_f(acc1 * rdenom[1] + bi);
    out[(size_t)(v0 + 2) * D + t] = relu_f(acc2 * rdenom[2] + bi);
    out[(size_t)(v0 + 3) * D + t] = relu_f(acc3 * rdenom[3] + bi);
}

// ---------------- self-loop-only rows v in [1024,8192): out = relu(h[v] + bias) ----------------
__global__ void gat_self(const float* __restrict__ h, const float* __restrict__ bias,
                         float* __restrict__ out, int DLOG)
{
    int idx = blockIdx.x * blockDim.x + threadIdx.x;
    int D = 1 << DLOG;
    int total = 7168 << DLOG;
    if (idx >= total) return;
    int c = idx & (D - 1);
    int n = 1024 + (idx >> DLOG);
    size_t off = ((size_t)n << DLOG) + c;
    out[off] = relu_f(h[off] + bias[c]);
}

// ---------------- mean-pool per image + final linear + log_softmax ----------------
__global__ void head_kernel(const float* __restrict__ x2, const float* __restrict__ ow,
                            const float* __restrict__ ob, float* __restrict__ out)
{
    __shared__ float pooled[128];
    __shared__ float logits[10];
    int b = blockIdx.x;   // 0..7
    int t = threadIdx.x;  // 0..127
    const float* p = x2 + (size_t)b * 1024 * 128;
    float acc = 0.f;
    for (int n = 0; n < 1024; ++n) acc += p[n * 128 + t];
    pooled[t] = acc * (1.f / 1024.f);
    __syncthreads();
    if (t < 10) {
        float l = ob[t];
        for (int c = 0; c < 128; ++c) l += pooled[c] * ow[c * 10 + t];
        logits[t] = l;
    }
    __syncthreads();
    if (t == 0) {
        float mx = logits[0];
        for (int j = 1; j < 10; ++j) mx = fmaxf(mx, logits[j]);
        float sum = 0.f;
        for (int j = 0; j < 10; ++j) sum += expf(logits[j] - mx);
        float lse = mx + logf(sum);
        for (int j = 0; j < 10; ++j) out[b * 10 + j] = logits[j] - lse;
    }
}

extern "C" void kernel_launch(void* const* d_in, const int* in_sizes, int n_in,
                              void* d_out, int out_size, void* d_ws, size_t ws_size,
                              hipStream_t stream)
{
    const float* images = (const float*)d_in[0];
    const float* c1w = (const float*)d_in[1];
    const float* c1b = (const float*)d_in[2];
    const float* bn1g = (const float*)d_in[3];
    const float* bn1b = (const float*)d_in[4];
    const float* bn1m = (const float*)d_in[5];
    const float* bn1v = (const float*)d_in[6];
    const float* c2w = (const float*)d_in[7];
    const float* c2b = (const float*)d_in[8];
    const float* bn2g = (const float*)d_in[9];
    const float* bn2b = (const float*)d_in[10];
    const float* bn2m = (const float*)d_in[11];
    const float* bn2v = (const float*)d_in[12];
    const float* g1w = (const float*)d_in[13];
    const float* g1as = (const float*)d_in[14];
    const float* g1ad = (const float*)d_in[15];
    const float* g1b = (const float*)d_in[16];
    const float* g2w = (const float*)d_in[17];
    const float* g2as = (const float*)d_in[18];
    const float* g2ad = (const float*)d_in[19];
    const float* g2b = (const float*)d_in[20];
    const float* ow = (const float*)d_in[21];
    const float* ob = (const float*)d_in[22];
    float* out = (float*)d_out;

    // workspace layout (floats); x1 aliases buf1 (dead after pool), x2 aliases x0 (dead after gemm1)
    float* ws = (float*)d_ws;
    float* buf1 = ws;               // 2,097,152 : conv1 out  (later x1 [8192,256])
    float* buf2 = ws + 2097152;     //   524,288 : pool out
    float* x0   = ws + 2621440;     // 1,048,576 : node feats [8192,128] (later x2)
    float* h1   = ws + 3670016;     // 2,097,152 : [8192,256]
    float* s1   = ws + 5767168;     //     8,192
    float* d1   = ws + 5775360;     //     8,192
    float* h2   = ws + 5783552;     // 1,048,576 : [8192,128]
    float* s2   = ws + 6832128;     //     8,192
    float* d2   = ws + 6840320;     //     8,192
    float* x1 = buf1;
    float* x2 = x0;

    conv1_fused<<<8192, 256, 0, stream>>>(images, c1w, c1b, bn1g, bn1b, bn1m, bn1v, buf1);
    pool2x2<<<2048, 256, 0, stream>>>(buf1, buf2);
    conv2_fused<<<512, 256, 0, stream>>>(buf2, c2w, c2b, bn2g, bn2b, bn2m, bn2v, x0);

    gemm_rb<128, 256, 16><<<512, 256, 0, stream>>>(x0, g1w, h1);
    score_kernel<<<2048, 256, 0, stream>>>(h1, g1as, g1ad, s1, d1, 256, 8192);
    gat_agg4<256><<<256, 256, 0, stream>>>(h1, s1, d1, g1b, x1);
    gat_self<<<7168, 256, 0, stream>>>(h1, g1b, x1, 8);

    gemm_rb<256, 128, 16><<<512, 128, 0, stream>>>(x1, g2w, h2);
    score_kernel<<<2048, 256, 0, stream>>>(h2, g2as, g2ad, s2, d2, 128, 8192);
    gat_agg4<128><<<256, 128, 0, stream>>>(h2, s2, d2, g2b, x2);
    gat_self<<<3584, 256, 0, stream>>>(h2, g2b, x2, 7);

    head_kernel<<<8, 128, 0, stream>>>(x2, ow, ob, out);
}

// Round 3
// 284.258 us; speedup vs baseline: 1.7373x; 1.2547x over previous
//
#include <hip/hip_runtime.h>
#include <math.h>

#define BN_EPS 1e-5f
#define NEG_SLOPE 0.2f

__device__ __forceinline__ float relu_f(float x) { return x > 0.f ? x : 0.f; }

// ---------------- conv1: 3->64, 3x3 SAME, 8x3x64x64, fused bias+BN+ReLU ----------------
__global__ void conv1_fused(const float* __restrict__ img,
                            const float* __restrict__ w, const float* __restrict__ cb,
                            const float* __restrict__ g, const float* __restrict__ bb,
                            const float* __restrict__ m, const float* __restrict__ vv,
                            float* __restrict__ out)
{
    int idx = blockIdx.x * blockDim.x + threadIdx.x;
    if (idx >= 8 * 64 * 64 * 64) return;
    int x = idx & 63, y = (idx >> 6) & 63, o = (idx >> 12) & 63, b = idx >> 18;
    const float* wp = w + o * 27;
    const float* ip = img + b * 3 * 4096;
    float acc = 0.f;
#pragma unroll
    for (int ky = 0; ky < 3; ++ky) {
        int yy = y + ky - 1;
        if ((unsigned)yy > 63u) continue;
#pragma unroll
        for (int kx = 0; kx < 3; ++kx) {
            int xx = x + kx - 1;
            if ((unsigned)xx > 63u) continue;
#pragma unroll
            for (int i = 0; i < 3; ++i)
                acc += ip[i * 4096 + yy * 64 + xx] * wp[i * 9 + ky * 3 + kx];
        }
    }
    float inv = g[o] / sqrtf(vv[o] + BN_EPS);
    float val = (acc + cb[o]) * inv + (bb[o] - m[o] * inv);
    out[idx] = relu_f(val);
}

// ---------------- 2x2 maxpool: 8x64x64x64 -> 8x64x32x32 ----------------
__global__ void pool2x2(const float* __restrict__ in, float* __restrict__ out)
{
    int idx = blockIdx.x * blockDim.x + threadIdx.x;
    if (idx >= 8 * 64 * 32 * 32) return;
    int x = idx & 31, y = (idx >> 5) & 31, c = (idx >> 10) & 63, b = idx >> 16;
    const float* p = in + ((b * 64 + c) * 64 + 2 * y) * 64 + 2 * x;
    out[idx] = fmaxf(fmaxf(p[0], p[1]), fmaxf(p[64], p[65]));
}

// helper: load 3x3 neighborhood with bounds -> r[9]
__device__ __forceinline__ void load9(const float* base, bool y0, bool y2, bool x0, bool x2,
                                      float* r)
{
    r[0] = (y0 && x0) ? base[-33] : 0.f;
    r[1] = y0 ? base[-32] : 0.f;
    r[2] = (y0 && x2) ? base[-31] : 0.f;
    r[3] = x0 ? base[-1] : 0.f;
    r[4] = base[0];
    r[5] = x2 ? base[1] : 0.f;
    r[6] = (y2 && x0) ? base[31] : 0.f;
    r[7] = y2 ? base[32] : 0.f;
    r[8] = (y2 && x2) ? base[33] : 0.f;
}

// ---------------- conv2: 64->128, 3x3 SAME. 4 co per thread, prefetched. ----------------
// grid: img(8) x cog(32) x quarter(4) = 1024 blocks, 256 threads
__global__ void conv2_fused(const float* __restrict__ in,
                            const float* __restrict__ w, const float* __restrict__ cb,
                            const float* __restrict__ g, const float* __restrict__ bb,
                            const float* __restrict__ m, const float* __restrict__ vv,
                            float* __restrict__ x0)
{
    int blk = blockIdx.x;
    int q = blk & 3;
    int cog = (blk >> 2) & 31;   // 4 output channels per group
    int b = blk >> 7;
    int t = threadIdx.x;
    int x = t & 31, y = (q << 3) + (t >> 5);

    const float* ip = in + b * 64 * 1024 + y * 32 + x;
    const float* wp = w + cog * 4 * 576;
    bool y0 = y >= 1, y2 = y <= 30, xx0 = x >= 1, x2 = x <= 30;

    float acc[4] = {0.f, 0.f, 0.f, 0.f};
    float rc[9], rn[9];
    load9(ip, y0, y2, xx0, x2, rc);

    for (int ci = 0; ci < 64; ++ci) {
        if (ci < 63) load9(ip + (ci + 1) * 1024, y0, y2, xx0, x2, rn);
        const float* wc = wp + ci * 9;
#pragma unroll
        for (int j = 0; j < 4; ++j) {
            const float* wj = wc + j * 576;
#pragma unroll
            for (int k = 0; k < 9; ++k)
                acc[j] += rc[k] * wj[k];
        }
#pragma unroll
        for (int k = 0; k < 9; ++k) rc[k] = rn[k];
    }

    int n = b * 1024 + y * 32 + x;
#pragma unroll
    for (int j = 0; j < 4; ++j) {
        int co = cog * 4 + j;
        float inv = g[co] / sqrtf(vv[co] + BN_EPS);
        float val = (acc[j] + cb[co]) * inv + (bb[co] - m[co] * inv);
        x0[n * 128 + co] = relu_f(val);
    }
}

// ---------------- tiled GEMM: C[8192,N] = A[8192,K] @ B[K,N], 64x64 tile, 4x4 micro ----------------
template <int K, int N>
__global__ void gemm_tiled(const float* __restrict__ A, const float* __restrict__ B,
                           float* __restrict__ C)
{
    __shared__ float As[16][64];
    __shared__ float Bs[16][64];
    int t = threadIdx.x;
    int m0 = blockIdx.x * 64;
    int n0 = blockIdx.y * 64;
    int tx = t & 15, ty = t >> 4;
    int am = t >> 2, akq = (t & 3) * 4;   // A-stage: row am, k-quad akq
    int bk = t >> 4, bn = (t & 15) * 4;   // B-stage: k-row bk, col-quad bn
    float acc[4][4] = {};

    for (int k0 = 0; k0 < K; k0 += 16) {
        float4 av = *(const float4*)&A[(size_t)(m0 + am) * K + k0 + akq];
        float4 bv = *(const float4*)&B[(size_t)(k0 + bk) * N + n0 + bn];
        __syncthreads();
        As[akq + 0][am] = av.x;
        As[akq + 1][am] = av.y;
        As[akq + 2][am] = av.z;
        As[akq + 3][am] = av.w;
        *(float4*)&Bs[bk][bn] = bv;
        __syncthreads();
#pragma unroll
        for (int kk = 0; kk < 16; ++kk) {
            float4 a4 = *(const float4*)&As[kk][ty * 4];
            float4 b4 = *(const float4*)&Bs[kk][tx * 4];
            float aa[4] = {a4.x, a4.y, a4.z, a4.w};
            float bb4[4] = {b4.x, b4.y, b4.z, b4.w};
#pragma unroll
            for (int i = 0; i < 4; ++i)
#pragma unroll
                for (int j = 0; j < 4; ++j)
                    acc[i][j] += aa[i] * bb4[j];
        }
    }
#pragma unroll
    for (int i = 0; i < 4; ++i) {
        float4 o = {acc[i][0], acc[i][1], acc[i][2], acc[i][3]};
        *(float4*)&C[(size_t)(m0 + ty * 4 + i) * N + n0 + tx * 4] = o;
    }
}

// ---------------- per-node attention scores: s = h@a_src, d = h@a_dst (one wave per row) ----------------
__global__ void score_kernel(const float* __restrict__ h, const float* __restrict__ asrc,
                             const float* __restrict__ adst, float* __restrict__ s,
                             float* __restrict__ d, int D, int N)
{
    int gt = blockIdx.x * blockDim.x + threadIdx.x;
    int wave = gt >> 6, lane = gt & 63;
    if (wave >= N) return;
    const float* hp = h + (size_t)wave * D;
    float ss = 0.f, dd = 0.f;
    for (int c = lane; c < D; c += 64) {
        float hv = hp[c];
        ss += hv * asrc[c];
        dd += hv * adst[c];
    }
    for (int off = 32; off; off >>= 1) {
        ss += __shfl_down(ss, off);
        dd += __shfl_down(dd, off);
    }
    if (lane == 0) { s[wave] = ss; d[wave] = dd; }
}

// ---------------- dense GAT aggregation: 4 dst rows per block, u-range split SPLIT ways ----------------
// block = D*SPLIT threads; grid = 256 blocks (v in [0,1024))
template <int D, int SPLIT>
__global__ void __launch_bounds__(512) gat_aggs(const float* __restrict__ h,
                                                const float* __restrict__ s,
                                                const float* __restrict__ dsc,
                                                const float* __restrict__ bias,
                                                float* __restrict__ out)
{
    __shared__ float ss[1024];
    __shared__ float4 alpha[1024];
    __shared__ float part[4 * SPLIT * D];
    __shared__ float rdenom[4];
    const int T = D * SPLIT;
    int v0 = blockIdx.x * 4;
    int t = threadIdx.x;
    int lane = t & 63, wave = t >> 6;

    for (int u = t; u < 1024; u += T) ss[u] = s[u];
    __syncthreads();

    if (wave < 4) {
        int j = wave;
        float dv = dsc[v0 + j];
        float ev[16];
        float lmax = -1e30f;
#pragma unroll
        for (int k = 0; k < 16; ++k) {
            float e = ss[lane + k * 64] + dv;
            e = e > 0.f ? e : NEG_SLOPE * e;
            ev[k] = e;
            lmax = fmaxf(lmax, e);
        }
#pragma unroll
        for (int off = 1; off < 64; off <<= 1)
            lmax = fmaxf(lmax, __shfl_xor(lmax, off));
        float lsum = 0.f;
#pragma unroll
        for (int k = 0; k < 16; ++k) {
            float ex = __expf(ev[k] - lmax);
            ((float*)&alpha[lane + k * 64])[j] = ex;
            lsum += ex;
        }
#pragma unroll
        for (int off = 1; off < 64; off <<= 1)
            lsum += __shfl_xor(lsum, off);
        if (lane == 0) rdenom[j] = 1.f / lsum;
    }
    __syncthreads();

    int col = t & (D - 1);
    int seg = t / D;
    const int UL = 1024 / SPLIT;
    int ub = seg * UL;
    float a0 = 0.f, a1 = 0.f, a2 = 0.f, a3 = 0.f;
    const float* hp = h + (size_t)ub * D + col;
#pragma unroll 4
    for (int u = 0; u < UL; ++u) {
        float hv = hp[(size_t)u * D];
        float4 a4 = alpha[ub + u];
        a0 += a4.x * hv;
        a1 += a4.y * hv;
        a2 += a4.z * hv;
        a3 += a4.w * hv;
    }
    part[(0 * SPLIT + seg) * D + col] = a0;
    part[(1 * SPLIT + seg) * D + col] = a1;
    part[(2 * SPLIT + seg) * D + col] = a2;
    part[(3 * SPLIT + seg) * D + col] = a3;
    __syncthreads();
    if (t < D) {
        float bi = bias[t];
#pragma unroll
        for (int j = 0; j < 4; ++j) {
            float sum = 0.f;
#pragma unroll
            for (int sg = 0; sg < SPLIT; ++sg) sum += part[(j * SPLIT + sg) * D + t];
            out[(size_t)(v0 + j) * D + t] = relu_f(sum * rdenom[j] + bi);
        }
    }
}

// ---------------- self-loop-only rows v in [1024,8192): out = relu(h[v] + bias) ----------------
__global__ void gat_self(const float* __restrict__ h, const float* __restrict__ bias,
                         float* __restrict__ out, int DLOG)
{
    int idx = blockIdx.x * blockDim.x + threadIdx.x;
    int D = 1 << DLOG;
    int total = 7168 << DLOG;
    if (idx >= total) return;
    int c = idx & (D - 1);
    int n = 1024 + (idx >> DLOG);
    size_t off = ((size_t)n << DLOG) + c;
    out[off] = relu_f(h[off] + bias[c]);
}

// ---------------- mean-pool per image + final linear + log_softmax ----------------
__global__ void head_kernel(const float* __restrict__ x2, const float* __restrict__ ow,
                            const float* __restrict__ ob, float* __restrict__ out)
{
    __shared__ float pooled[128];
    __shared__ float logits[10];
    int b = blockIdx.x;   // 0..7
    int t = threadIdx.x;  // 0..127
    const float* p = x2 + (size_t)b * 1024 * 128;
    float acc = 0.f;
    for (int n = 0; n < 1024; ++n) acc += p[n * 128 + t];
    pooled[t] = acc * (1.f / 1024.f);
    __syncthreads();
    if (t < 10) {
        float l = ob[t];
        for (int c = 0; c < 128; ++c) l += pooled[c] * ow[c * 10 + t];
        logits[t] = l;
    }
    __syncthreads();
    if (t == 0) {
        float mx = logits[0];
        for (int j = 1; j < 10; ++j) mx = fmaxf(mx, logits[j]);
        float sum = 0.f;
        for (int j = 0; j < 10; ++j) sum += expf(logits[j] - mx);
        float lse = mx + logf(sum);
        for (int j = 0; j < 10; ++j) out[b * 10 + j] = logits[j] - lse;
    }
}

extern "C" void kernel_launch(void* const* d_in, const int* in_sizes, int n_in,
                              void* d_out, int out_size, void* d_ws, size_t ws_size,
                              hipStream_t stream)
{
    const float* images = (const float*)d_in[0];
    const float* c1w = (const float*)d_in[1];
    const float* c1b = (const float*)d_in[2];
    const float* bn1g = (const float*)d_in[3];
    const float* bn1b = (const float*)d_in[4];
    const float* bn1m = (const float*)d_in[5];
    const float* bn1v = (const float*)d_in[6];
    const float* c2w = (const float*)d_in[7];
    const float* c2b = (const float*)d_in[8];
    const float* bn2g = (const float*)d_in[9];
    const float* bn2b = (const float*)d_in[10];
    const float* bn2m = (const float*)d_in[11];
    const float* bn2v = (const float*)d_in[12];
    const float* g1w = (const float*)d_in[13];
    const float* g1as = (const float*)d_in[14];
    const float* g1ad = (const float*)d_in[15];
    const float* g1b = (const float*)d_in[16];
    const float* g2w = (const float*)d_in[17];
    const float* g2as = (const float*)d_in[18];
    const float* g2ad = (const float*)d_in[19];
    const float* g2b = (const float*)d_in[20];
    const float* ow = (const float*)d_in[21];
    const float* ob = (const float*)d_in[22];
    float* out = (float*)d_out;

    float* ws = (float*)d_ws;
    float* buf1 = ws;               // conv1 out (later x1 [8192,256])
    float* buf2 = ws + 2097152;     // pool out
    float* x0   = ws + 2621440;     // node feats [8192,128] (later x2)
    float* h1   = ws + 3670016;     // [8192,256]
    float* s1   = ws + 5767168;
    float* d1   = ws + 5775360;
    float* h2   = ws + 5783552;     // [8192,128]
    float* s2   = ws + 6832128;
    float* d2   = ws + 6840320;
    float* x1 = buf1;
    float* x2 = x0;

    conv1_fused<<<8192, 256, 0, stream>>>(images, c1w, c1b, bn1g, bn1b, bn1m, bn1v, buf1);
    pool2x2<<<2048, 256, 0, stream>>>(buf1, buf2);
    conv2_fused<<<1024, 256, 0, stream>>>(buf2, c2w, c2b, bn2g, bn2b, bn2m, bn2v, x0);

    gemm_tiled<128, 256><<<dim3(128, 4), 256, 0, stream>>>(x0, g1w, h1);
    score_kernel<<<2048, 256, 0, stream>>>(h1, g1as, g1ad, s1, d1, 256, 8192);
    gat_aggs<256, 2><<<256, 512, 0, stream>>>(h1, s1, d1, g1b, x1);
    gat_self<<<7168, 256, 0, stream>>>(h1, g1b, x1, 8);

    gemm_tiled<256, 128><<<dim3(128, 2), 256, 0, stream>>>(x1, g2w, h2);
    score_kernel<<<2048, 256, 0, stream>>>(h2, g2as, g2ad, s2, d2, 128, 8192);
    gat_aggs<128, 4><<<256, 512, 0, stream>>>(h2, s2, d2, g2b, x2);
    gat_self<<<3584, 256, 0, stream>>>(h2, g2b, x2, 7);

    head_kernel<<<8, 128, 0, stream>>>(x2, ow, ob, out);
}

// Round 4
// 236.097 us; speedup vs baseline: 2.0917x; 1.2040x over previous
//
#include <hip/hip_runtime.h>
#include <math.h>

#define BN_EPS 1e-5f
#define NEG_SLOPE 0.2f

__device__ __forceinline__ float relu_f(float x) { return x > 0.f ? x : 0.f; }
__device__ __forceinline__ float leaky_f(float z) { return z > 0.f ? z : NEG_SLOPE * z; }

// ---------------- conv1 (3->64, 3x3 SAME) fused with bias+BN+ReLU+2x2maxpool ----------------
// grid 512 = b(8) x cog(16) x q(4); 256 threads = one pooled position each, 4 co
__global__ void conv1_pool(const float* __restrict__ img, const float* __restrict__ w,
                           const float* __restrict__ cb, const float* __restrict__ g,
                           const float* __restrict__ bb, const float* __restrict__ m,
                           const float* __restrict__ vv, float* __restrict__ out)
{
    int blk = blockIdx.x;
    int q = blk & 3, cog = (blk >> 2) & 15, b = blk >> 6;
    int t = threadIdx.x;
    int x = t & 31, y = (q << 3) + (t >> 5);   // pooled coords in 32x32

    float acc[4][4] = {};   // [co j][py*2+px]
#pragma unroll
    for (int ci = 0; ci < 3; ++ci) {
        const float* ib = img + (b * 3 + ci) * 4096;
        float rv[4][4];
#pragma unroll
        for (int r = 0; r < 4; ++r) {
            int yy = 2 * y - 1 + r;
            bool yok = (unsigned)yy < 64u;
            const float* p = ib + yy * 64 + 2 * x;
            float2 c01 = yok ? *(const float2*)p : make_float2(0.f, 0.f);
            rv[r][1] = c01.x;
            rv[r][2] = c01.y;
            rv[r][0] = (yok && x > 0) ? p[-1] : 0.f;
            rv[r][3] = (yok && x < 31) ? p[2] : 0.f;
        }
#pragma unroll
        for (int j = 0; j < 4; ++j) {
            const float* wj = w + ((cog * 4 + j) * 3 + ci) * 9;
#pragma unroll
            for (int ky = 0; ky < 3; ++ky)
#pragma unroll
                for (int kx = 0; kx < 3; ++kx) {
                    float wvv = wj[ky * 3 + kx];
#pragma unroll
                    for (int py = 0; py < 2; ++py)
#pragma unroll
                        for (int px = 0; px < 2; ++px)
                            acc[j][py * 2 + px] += rv[py + ky][px + kx] * wvv;
                }
        }
    }
#pragma unroll
    for (int j = 0; j < 4; ++j) {
        int co = cog * 4 + j;
        float inv = g[co] / sqrtf(vv[co] + BN_EPS);
        float sh = cb[co] * inv + (bb[co] - m[co] * inv);
        float v0 = relu_f(acc[j][0] * inv + sh);
        float v1 = relu_f(acc[j][1] * inv + sh);
        float v2 = relu_f(acc[j][2] * inv + sh);
        float v3 = relu_f(acc[j][3] * inv + sh);
        out[((b * 64 + co) * 32 + y) * 32 + x] = fmaxf(fmaxf(v0, v1), fmaxf(v2, v3));
    }
}

// ---------------- conv2: 64->128, 3x3 SAME; 4 x-pos x 4 co per thread, prefetched ----------------
__device__ __forceinline__ void c2load(const float* cbase, int y, int x4, bool xl, bool xr,
                                       float r6[3][6])
{
#pragma unroll
    for (int r = 0; r < 3; ++r) {
        int yy = y - 1 + r;
        bool yok = (unsigned)yy < 32u;
        const float* p = cbase + yy * 32 + x4;
        float4 f = yok ? *(const float4*)p : make_float4(0.f, 0.f, 0.f, 0.f);
        r6[r][1] = f.x; r6[r][2] = f.y; r6[r][3] = f.z; r6[r][4] = f.w;
        r6[r][0] = (yok && xl) ? p[-1] : 0.f;
        r6[r][5] = (yok && xr) ? p[4] : 0.f;
    }
}

// grid 512 = b(8) x cog(32) x half(2); 128 threads
__global__ void conv2_fused(const float* __restrict__ in, const float* __restrict__ w,
                            const float* __restrict__ cb, const float* __restrict__ g,
                            const float* __restrict__ bb, const float* __restrict__ m,
                            const float* __restrict__ vv, float* __restrict__ x0)
{
    int blk = blockIdx.x;
    int half = blk & 1, cog = (blk >> 1) & 31, b = blk >> 6;
    int t = threadIdx.x;
    int x4 = (t & 7) * 4;
    int y = half * 16 + (t >> 3);
    bool xl = x4 > 0, xr = x4 < 28;
    const float* ibase = in + b * 64 * 1024;

    float rc[3][6], rn[3][6];
    c2load(ibase, y, x4, xl, xr, rc);

    float acc[4][4] = {};
    for (int ci = 0; ci < 64; ++ci) {
        if (ci < 63) c2load(ibase + (ci + 1) * 1024, y, x4, xl, xr, rn);
#pragma unroll
        for (int j = 0; j < 4; ++j) {
            const float* wj = w + ((cog * 4 + j) * 64 + ci) * 9;
#pragma unroll
            for (int ky = 0; ky < 3; ++ky)
#pragma unroll
                for (int kx = 0; kx < 3; ++kx) {
                    float wvv = wj[ky * 3 + kx];
#pragma unroll
                    for (int p = 0; p < 4; ++p)
                        acc[j][p] += rc[ky][p + kx] * wvv;
                }
        }
#pragma unroll
        for (int r = 0; r < 3; ++r)
#pragma unroll
            for (int k = 0; k < 6; ++k) rc[r][k] = rn[r][k];
    }

#pragma unroll
    for (int j = 0; j < 4; ++j) {
        int co = cog * 4 + j;
        float inv = g[co] / sqrtf(vv[co] + BN_EPS);
        float sh = cb[co] * inv + (bb[co] - m[co] * inv);
#pragma unroll
        for (int p = 0; p < 4; ++p) {
            int n = b * 1024 + y * 32 + x4 + p;
            x0[(size_t)n * 128 + co] = relu_f(acc[j][p] * inv + sh);
        }
    }
}

// ---------------- tiled GEMM: C[8192,N] = A[8192,K] @ B[K,N], 64x64 tile, 4x4 micro ----------------
template <int K, int N>
__global__ void gemm_tiled(const float* __restrict__ A, const float* __restrict__ B,
                           float* __restrict__ C)
{
    __shared__ float As[16][64];
    __shared__ float Bs[16][64];
    int t = threadIdx.x;
    int m0 = blockIdx.x * 64;
    int n0 = blockIdx.y * 64;
    int tx = t & 15, ty = t >> 4;
    int am = t >> 2, akq = (t & 3) * 4;
    int bk = t >> 4, bn = (t & 15) * 4;
    float acc[4][4] = {};

    for (int k0 = 0; k0 < K; k0 += 16) {
        float4 av = *(const float4*)&A[(size_t)(m0 + am) * K + k0 + akq];
        float4 bv = *(const float4*)&B[(size_t)(k0 + bk) * N + n0 + bn];
        __syncthreads();
        As[akq + 0][am] = av.x;
        As[akq + 1][am] = av.y;
        As[akq + 2][am] = av.z;
        As[akq + 3][am] = av.w;
        *(float4*)&Bs[bk][bn] = bv;
        __syncthreads();
#pragma unroll
        for (int kk = 0; kk < 16; ++kk) {
            float4 a4 = *(const float4*)&As[kk][ty * 4];
            float4 b4 = *(const float4*)&Bs[kk][tx * 4];
            float aa[4] = {a4.x, a4.y, a4.z, a4.w};
            float bb4[4] = {b4.x, b4.y, b4.z, b4.w};
#pragma unroll
            for (int i = 0; i < 4; ++i)
#pragma unroll
                for (int j = 0; j < 4; ++j)
                    acc[i][j] += aa[i] * bb4[j];
        }
    }
#pragma unroll
    for (int i = 0; i < 4; ++i) {
        float4 o = {acc[i][0], acc[i][1], acc[i][2], acc[i][3]};
        *(float4*)&C[(size_t)(m0 + ty * 4 + i) * N + n0 + tx * 4] = o;
    }
}

// ---------------- attention scores for nodes < 1024 (one wave per row) ----------------
__global__ void score_kernel(const float* __restrict__ h, const float* __restrict__ asrc,
                             const float* __restrict__ adst, float* __restrict__ s,
                             float* __restrict__ d, int D, int N)
{
    int gt = blockIdx.x * blockDim.x + threadIdx.x;
    int wave = gt >> 6, lane = gt & 63;
    if (wave >= N) return;
    const float* hp = h + (size_t)wave * D;
    float ss = 0.f, dd = 0.f;
    for (int c = lane; c < D; c += 64) {
        float hv = hp[c];
        ss += hv * asrc[c];
        dd += hv * adst[c];
    }
    for (int off = 32; off; off >>= 1) {
        ss += __shfl_down(ss, off);
        dd += __shfl_down(dd, off);
    }
    if (lane == 0) { s[wave] = ss; d[wave] = dd; }
}

// ---------------- GAT aggregation as split-K GEMM with in-LDS alpha generation ----------------
// C[v,c] = sum_u exp(leaky(s[u]+d[v]) - m[v]) * h[u,c];  m[v] = leaky(smax + d[v])
// grid (16, D/64, KS); 256 threads; writes pacc[kz][1024][D] and pden[kz][1024]
template <int D, int KS>
__global__ void gat_agg_gemm(const float* __restrict__ h, const float* __restrict__ s,
                             const float* __restrict__ d, float* __restrict__ pacc,
                             float* __restrict__ pden)
{
    __shared__ float Ss[1024];
    __shared__ float As[16][64];
    __shared__ float Bs[16][64];
    __shared__ float red[4];
    __shared__ float part[16][64];

    const int CH = 1024 / KS;
    int t = threadIdx.x;
    int m0 = blockIdx.x * 64;
    int n0 = blockIdx.y * 64;
    int kz = blockIdx.z;
    int tx = t & 15, ty = t >> 4;
    int av4 = tx * 4;   // 4 consecutive v per thread for A-gen

    // stage s + global max
    float4 s4 = *(const float4*)&s[t * 4];
    *(float4*)&Ss[t * 4] = s4;
    float lm = fmaxf(fmaxf(s4.x, s4.y), fmaxf(s4.z, s4.w));
#pragma unroll
    for (int off = 1; off < 64; off <<= 1) lm = fmaxf(lm, __shfl_xor(lm, off));
    if ((t & 63) == 0) red[t >> 6] = lm;
    __syncthreads();
    float smax = fmaxf(fmaxf(red[0], red[1]), fmaxf(red[2], red[3]));

    float4 dv = *(const float4*)&d[m0 + av4];
    float4 mv = {leaky_f(smax + dv.x), leaky_f(smax + dv.y),
                 leaky_f(smax + dv.z), leaky_f(smax + dv.w)};
    float4 dsum = {0.f, 0.f, 0.f, 0.f};
    float acc[4][4] = {};

    for (int k0 = kz * CH; k0 < kz * CH + CH; k0 += 16) {
        float4 bv = *(const float4*)&h[(size_t)(k0 + ty) * D + n0 + tx * 4];
        float su = Ss[k0 + ty];
        float4 avv;
        avv.x = __expf(leaky_f(su + dv.x) - mv.x);
        avv.y = __expf(leaky_f(su + dv.y) - mv.y);
        avv.z = __expf(leaky_f(su + dv.z) - mv.z);
        avv.w = __expf(leaky_f(su + dv.w) - mv.w);
        dsum.x += avv.x; dsum.y += avv.y; dsum.z += avv.z; dsum.w += avv.w;
        __syncthreads();
        *(float4*)&As[ty][av4] = avv;     // As[u-local][v-local]
        *(float4*)&Bs[ty][tx * 4] = bv;   // Bs[u-local][c-local]
        __syncthreads();
#pragma unroll
        for (int kk = 0; kk < 16; ++kk) {
            float4 a4 = *(const float4*)&As[kk][ty * 4];
            float4 b4 = *(const float4*)&Bs[kk][tx * 4];
            float aa[4] = {a4.x, a4.y, a4.z, a4.w};
            float bb4[4] = {b4.x, b4.y, b4.z, b4.w};
#pragma unroll
            for (int i = 0; i < 4; ++i)
#pragma unroll
                for (int j = 0; j < 4; ++j)
                    acc[i][j] += aa[i] * bb4[j];
        }
    }

    __syncthreads();
    *(float4*)&part[ty][av4] = dsum;
    __syncthreads();

#pragma unroll
    for (int i = 0; i < 4; ++i) {
        int r = ty * 4 + i;
        float4 o = {acc[i][0], acc[i][1], acc[i][2], acc[i][3]};
        *(float4*)&pacc[((size_t)kz * 1024 + m0 + r) * D + n0 + tx * 4] = o;
    }
    if (t < 64) {
        float den = 0.f;
#pragma unroll
        for (int u = 0; u < 16; ++u) den += part[u][t];
        pden[kz * 1024 + m0 + t] = den;   // same value from every n0-block: benign
    }
}

// combine split-K partials: out[v,c] = relu(sum_ks pacc / sum_ks pden + bias)
template <int D, int KS>
__global__ void gat_combine(const float* __restrict__ pacc, const float* __restrict__ pden,
                            const float* __restrict__ bias, float* __restrict__ out)
{
    int idx = blockIdx.x * blockDim.x + threadIdx.x;
    if (idx >= 1024 * D / 4) return;
    int c4 = idx & (D / 4 - 1);
    int v = idx / (D / 4);
    float4 a = {0.f, 0.f, 0.f, 0.f};
    float den = 0.f;
#pragma unroll
    for (int ks = 0; ks < KS; ++ks) {
        float4 p = ((const float4*)pacc)[(size_t)(ks * 1024 + v) * (D / 4) + c4];
        a.x += p.x; a.y += p.y; a.z += p.z; a.w += p.w;
        den += pden[ks * 1024 + v];
    }
    float rd = 1.f / den;
    float4 bz = ((const float4*)bias)[c4];
    float4 o = {relu_f(a.x * rd + bz.x), relu_f(a.y * rd + bz.y),
                relu_f(a.z * rd + bz.z), relu_f(a.w * rd + bz.w)};
    ((float4*)out)[(size_t)v * (D / 4) + c4] = o;
}

// ---------------- self-loop-only rows v in [1024,8192): out = relu(h[v] + bias) ----------------
template <int D>
__global__ void gat_self4(const float* __restrict__ h, const float* __restrict__ bias,
                          float* __restrict__ out)
{
    int idx = blockIdx.x * blockDim.x + threadIdx.x;
    if (idx >= 7168 * D / 4) return;
    int c4 = idx & (D / 4 - 1);
    int n = 1024 + idx / (D / 4);
    float4 v = ((const float4*)h)[(size_t)n * (D / 4) + c4];
    float4 bz = ((const float4*)bias)[c4];
    float4 o = {relu_f(v.x + bz.x), relu_f(v.y + bz.y),
                relu_f(v.z + bz.z), relu_f(v.w + bz.w)};
    ((float4*)out)[(size_t)n * (D / 4) + c4] = o;
}

// ---------------- mean-pool stage 1: 128 blocks, each sums 64 rows ----------------
__global__ void pool_part(const float* __restrict__ x2, float* __restrict__ part)
{
    int b = blockIdx.x >> 4, seg = blockIdx.x & 15, t = threadIdx.x;   // 128 threads
    const float* p = x2 + ((size_t)b * 1024 + seg * 64) * 128 + t;
    float acc = 0.f;
#pragma unroll 8
    for (int n = 0; n < 64; ++n) acc += p[(size_t)n * 128];
    part[(b * 16 + seg) * 128 + t] = acc;
}

// ---------------- head: reduce partials + linear + log_softmax ----------------
__global__ void head_kernel(const float* __restrict__ part, const float* __restrict__ ow,
                            const float* __restrict__ ob, float* __restrict__ out)
{
    __shared__ float pooled[128];
    __shared__ float logits[10];
    int b = blockIdx.x, t = threadIdx.x;   // 8 blocks, 128 threads
    float acc = 0.f;
#pragma unroll
    for (int sgi = 0; sgi < 16; ++sgi) acc += part[(b * 16 + sgi) * 128 + t];
    pooled[t] = acc * (1.f / 1024.f);
    __syncthreads();
    if (t < 10) {
        float l = ob[t];
        for (int c = 0; c < 128; ++c) l += pooled[c] * ow[c * 10 + t];
        logits[t] = l;
    }
    __syncthreads();
    if (t == 0) {
        float mx = logits[0];
        for (int j = 1; j < 10; ++j) mx = fmaxf(mx, logits[j]);
        float sum = 0.f;
        for (int j = 0; j < 10; ++j) sum += expf(logits[j] - mx);
        float lse = mx + logf(sum);
        for (int j = 0; j < 10; ++j) out[b * 10 + j] = logits[j] - lse;
    }
}

extern "C" void kernel_launch(void* const* d_in, const int* in_sizes, int n_in,
                              void* d_out, int out_size, void* d_ws, size_t ws_size,
                              hipStream_t stream)
{
    const float* images = (const float*)d_in[0];
    const float* c1w = (const float*)d_in[1];
    const float* c1b = (const float*)d_in[2];
    const float* bn1g = (const float*)d_in[3];
    const float* bn1b = (const float*)d_in[4];
    const float* bn1m = (const float*)d_in[5];
    const float* bn1v = (const float*)d_in[6];
    const float* c2w = (const float*)d_in[7];
    const float* c2b = (const float*)d_in[8];
    const float* bn2g = (const float*)d_in[9];
    const float* bn2b = (const float*)d_in[10];
    const float* bn2m = (const float*)d_in[11];
    const float* bn2v = (const float*)d_in[12];
    const float* g1w = (const float*)d_in[13];
    const float* g1as = (const float*)d_in[14];
    const float* g1ad = (const float*)d_in[15];
    const float* g1b = (const float*)d_in[16];
    const float* g2w = (const float*)d_in[17];
    const float* g2as = (const float*)d_in[18];
    const float* g2ad = (const float*)d_in[19];
    const float* g2b = (const float*)d_in[20];
    const float* ow = (const float*)d_in[21];
    const float* ob = (const float*)d_in[22];
    float* out = (float*)d_out;

    float* ws = (float*)d_ws;
    float* x1    = ws;                  // [8192,256] (layer1 out; dead after gemm2 -> pacc2)
    float* buf2  = ws + 2097152;        // pooled conv1 out [8,64,32,32]; later pden/part
    float* x0    = ws + 2621440;        // node feats [8192,128]; later pacc1, then x2
    float* h1    = ws + 3670016;        // [8192,256]
    float* s1    = ws + 5767168;        // 1024 used
    float* d1    = ws + 5775360;        // 1024 used
    float* h2    = ws + 5783552;        // [8192,128]
    float* s2    = ws + 6832128;
    float* d2    = ws + 6840320;
    float* part  = buf2;                // 8*16*128 = 16384 (used at end)
    float* pden1 = buf2 + 32768;        // 4*1024
    float* pden2 = buf2 + 49152;        // 8*1024
    float* pacc1 = x0;                  // 4*1024*256 = 1,048,576 (x0 dead after gemm1)
    float* pacc2 = x1;                  // 8*1024*128 = 1,048,576 (x1 dead after gemm2)
    float* x2 = x0;

    conv1_pool<<<512, 256, 0, stream>>>(images, c1w, c1b, bn1g, bn1b, bn1m, bn1v, buf2);
    conv2_fused<<<512, 128, 0, stream>>>(buf2, c2w, c2b, bn2g, bn2b, bn2m, bn2v, x0);

    gemm_tiled<128, 256><<<dim3(128, 4), 256, 0, stream>>>(x0, g1w, h1);
    score_kernel<<<256, 256, 0, stream>>>(h1, g1as, g1ad, s1, d1, 256, 1024);
    gat_agg_gemm<256, 4><<<dim3(16, 4, 4), 256, 0, stream>>>(h1, s1, d1, pacc1, pden1);
    gat_combine<256, 4><<<256, 256, 0, stream>>>(pacc1, pden1, g1b, x1);
    gat_self4<256><<<1792, 256, 0, stream>>>(h1, g1b, x1);

    gemm_tiled<256, 128><<<dim3(128, 2), 256, 0, stream>>>(x1, g2w, h2);
    score_kernel<<<256, 256, 0, stream>>>(h2, g2as, g2ad, s2, d2, 128, 1024);
    gat_agg_gemm<128, 8><<<dim3(16, 2, 8), 256, 0, stream>>>(h2, s2, d2, pacc2, pden2);
    gat_combine<128, 8><<<128, 256, 0, stream>>>(pacc2, pden2, g2b, x2);
    gat_self4<128><<<896, 256, 0, stream>>>(h2, g2b, x2);

    pool_part<<<128, 128, 0, stream>>>(x2, part);
    head_kernel<<<8, 128, 0, stream>>>(part, ow, ob, out);
}

// Round 5
// 217.446 us; speedup vs baseline: 2.2711x; 1.0858x over previous
//
#include <hip/hip_runtime.h>
#include <math.h>

#define BN_EPS 1e-5f
#define NEG_SLOPE 0.2f

__device__ __forceinline__ float relu_f(float x) { return x > 0.f ? x : 0.f; }
__device__ __forceinline__ float leaky_f(float z) { return z > 0.f ? z : NEG_SLOPE * z; }

// ---------------- conv1 (3->64, 3x3 SAME) fused bias+BN+ReLU+2x2maxpool ----------------
// grid 512 = b(8) x cog(16) x q(4); 256 threads = one pooled position, 4 co
__global__ void conv1_pool(const float* __restrict__ img, const float* __restrict__ w,
                           const float* __restrict__ cb, const float* __restrict__ g,
                           const float* __restrict__ bb, const float* __restrict__ m,
                           const float* __restrict__ vv, float* __restrict__ out)
{
    int blk = blockIdx.x;
    int q = blk & 3, cog = (blk >> 2) & 15, b = blk >> 6;
    int t = threadIdx.x;
    int x = t & 31, y = (q << 3) + (t >> 5);

    float acc[4][4] = {};
#pragma unroll
    for (int ci = 0; ci < 3; ++ci) {
        const float* ib = img + (b * 3 + ci) * 4096;
        float rv[4][4];
#pragma unroll
        for (int r = 0; r < 4; ++r) {
            int yy = 2 * y - 1 + r;
            bool yok = (unsigned)yy < 64u;
            const float* p = ib + yy * 64 + 2 * x;
            float2 c01 = yok ? *(const float2*)p : make_float2(0.f, 0.f);
            rv[r][1] = c01.x;
            rv[r][2] = c01.y;
            rv[r][0] = (yok && x > 0) ? p[-1] : 0.f;
            rv[r][3] = (yok && x < 31) ? p[2] : 0.f;
        }
#pragma unroll
        for (int j = 0; j < 4; ++j) {
            const float* wj = w + ((cog * 4 + j) * 3 + ci) * 9;
#pragma unroll
            for (int ky = 0; ky < 3; ++ky)
#pragma unroll
                for (int kx = 0; kx < 3; ++kx) {
                    float wvv = wj[ky * 3 + kx];
#pragma unroll
                    for (int py = 0; py < 2; ++py)
#pragma unroll
                        for (int px = 0; px < 2; ++px)
                            acc[j][py * 2 + px] += rv[py + ky][px + kx] * wvv;
                }
        }
    }
#pragma unroll
    for (int j = 0; j < 4; ++j) {
        int co = cog * 4 + j;
        float inv = g[co] / sqrtf(vv[co] + BN_EPS);
        float sh = cb[co] * inv + (bb[co] - m[co] * inv);
        float v0 = relu_f(acc[j][0] * inv + sh);
        float v1 = relu_f(acc[j][1] * inv + sh);
        float v2 = relu_f(acc[j][2] * inv + sh);
        float v3 = relu_f(acc[j][3] * inv + sh);
        out[((b * 64 + co) * 32 + y) * 32 + x] = fmaxf(fmaxf(v0, v1), fmaxf(v2, v3));
    }
}

// ---------------- conv2: 64->128, 3x3 SAME. 2 x-pos x 4 co per thread, 256thr, 512 blocks ----------------
// grid 512 = b(8) x cog(32) x half(2); 256 threads: x2p=(t&15)*2, y=half*16+(t>>4)
__global__ void conv2_fused(const float* __restrict__ in, const float* __restrict__ w,
                            const float* __restrict__ cb, const float* __restrict__ g,
                            const float* __restrict__ bb, const float* __restrict__ m,
                            const float* __restrict__ vv, float* __restrict__ x0)
{
    int blk = blockIdx.x;
    int half = blk & 1, cog = (blk >> 1) & 31, b = blk >> 6;
    int t = threadIdx.x;
    int x2p = (t & 15) * 2;
    int y = half * 16 + (t >> 4);
    bool xnz = x2p != 0;
    bool xhi = x2p == 30;
    const float* ibase = in + b * 64 * 1024;
    int xb = xnz ? x2p - 1 : 0;

    float acc[4][2] = {};

#pragma unroll 2
    for (int ci = 0; ci < 64; ++ci) {
        const float* cb2 = ibase + ci * 1024;
        float rc[3][4];
#pragma unroll
        for (int r = 0; r < 3; ++r) {
            int yy = y - 1 + r;
            bool yok = (unsigned)yy < 32u;
            const float* p = cb2 + yy * 32 + xb;
            float4 f = yok ? *(const float4*)p : make_float4(0.f, 0.f, 0.f, 0.f);
            rc[r][0] = xnz ? f.x : 0.f;
            rc[r][1] = xnz ? f.y : f.x;
            rc[r][2] = xnz ? f.z : f.y;
            float r3 = xnz ? f.w : f.z;
            rc[r][3] = xhi ? 0.f : r3;
        }
#pragma unroll
        for (int j = 0; j < 4; ++j) {
            const float* wj = w + ((cog * 4 + j) * 64 + ci) * 9;
#pragma unroll
            for (int ky = 0; ky < 3; ++ky)
#pragma unroll
                for (int kx = 0; kx < 3; ++kx) {
                    float wvv = wj[ky * 3 + kx];
                    acc[j][0] += rc[ky][kx] * wvv;
                    acc[j][1] += rc[ky][kx + 1] * wvv;
                }
        }
    }

    float o0[4], o1[4];
#pragma unroll
    for (int j = 0; j < 4; ++j) {
        int co = cog * 4 + j;
        float inv = g[co] / sqrtf(vv[co] + BN_EPS);
        float sh = cb[co] * inv + (bb[co] - m[co] * inv);
        o0[j] = relu_f(acc[j][0] * inv + sh);
        o1[j] = relu_f(acc[j][1] * inv + sh);
    }
    int n0 = b * 1024 + y * 32 + x2p;
    float4 s0 = {o0[0], o0[1], o0[2], o0[3]};
    float4 s1 = {o1[0], o1[1], o1[2], o1[3]};
    *(float4*)&x0[(size_t)n0 * 128 + cog * 4] = s0;
    *(float4*)&x0[(size_t)(n0 + 1) * 128 + cog * 4] = s1;
}

// ---------------- tiled GEMM: 32x64 tile, 128 threads, 4x4 micro ----------------
// grid (M/32, N/64)
template <int K, int N>
__global__ void gemm32(const float* __restrict__ A, const float* __restrict__ B,
                       float* __restrict__ C)
{
    __shared__ float As[16][32];
    __shared__ float Bs[16][64];
    int t = threadIdx.x;
    int m0 = blockIdx.x * 32;
    int n0 = blockIdx.y * 64;
    int tx = t & 15, ty = t >> 4;          // micro: rows ty*4.., cols tx*4..
    int am = t >> 2, akq = (t & 3) * 4;    // A-stage
    float acc[4][4] = {};

    for (int k0 = 0; k0 < K; k0 += 16) {
        float4 av = *(const float4*)&A[(size_t)(m0 + am) * K + k0 + akq];
        float4 bv0 = *(const float4*)&B[(size_t)(k0 + ty) * N + n0 + tx * 4];
        float4 bv1 = *(const float4*)&B[(size_t)(k0 + 8 + ty) * N + n0 + tx * 4];
        __syncthreads();
        As[akq + 0][am] = av.x;
        As[akq + 1][am] = av.y;
        As[akq + 2][am] = av.z;
        As[akq + 3][am] = av.w;
        *(float4*)&Bs[ty][tx * 4] = bv0;
        *(float4*)&Bs[ty + 8][tx * 4] = bv1;
        __syncthreads();
#pragma unroll
        for (int kk = 0; kk < 16; ++kk) {
            float4 a4 = *(const float4*)&As[kk][ty * 4];
            float4 b4 = *(const float4*)&Bs[kk][tx * 4];
            float aa[4] = {a4.x, a4.y, a4.z, a4.w};
            float bb4[4] = {b4.x, b4.y, b4.z, b4.w};
#pragma unroll
            for (int i = 0; i < 4; ++i)
#pragma unroll
                for (int j = 0; j < 4; ++j)
                    acc[i][j] += aa[i] * bb4[j];
        }
    }
#pragma unroll
    for (int i = 0; i < 4; ++i) {
        float4 o = {acc[i][0], acc[i][1], acc[i][2], acc[i][3]};
        *(float4*)&C[(size_t)(m0 + ty * 4 + i) * N + n0 + tx * 4] = o;
    }
}

// ---------------- attention scores for nodes < 1024 (one wave per row) ----------------
__global__ void score_kernel(const float* __restrict__ h, const float* __restrict__ asrc,
                             const float* __restrict__ adst, float* __restrict__ s,
                             float* __restrict__ d, int D, int N)
{
    int gt = blockIdx.x * blockDim.x + threadIdx.x;
    int wave = gt >> 6, lane = gt & 63;
    if (wave >= N) return;
    const float* hp = h + (size_t)wave * D;
    float ss = 0.f, dd = 0.f;
    for (int c = lane; c < D; c += 64) {
        float hv = hp[c];
        ss += hv * asrc[c];
        dd += hv * adst[c];
    }
    for (int off = 32; off; off >>= 1) {
        ss += __shfl_down(ss, off);
        dd += __shfl_down(dd, off);
    }
    if (lane == 0) { s[wave] = ss; d[wave] = dd; }
}

// ---------------- GAT aggregation as split-K GEMM, 32x64 tile, 128 threads ----------------
// C[v,c] = sum_u exp(leaky(s[u]+d[v]) - m[v]) * h[u,c];  m[v] = leaky(smax + d[v])
// grid (32, D/64, KS); 128 threads
template <int D, int KS>
__global__ void gat_agg_gemm(const float* __restrict__ h, const float* __restrict__ s,
                             const float* __restrict__ d, float* __restrict__ pacc,
                             float* __restrict__ pden)
{
    __shared__ float Ss[1024];
    __shared__ float As[16][32];
    __shared__ float Bs[16][64];
    __shared__ float red[2];
    __shared__ float part[16][32];

    const int CH = 1024 / KS;
    int t = threadIdx.x;
    int m0 = blockIdx.x * 32;
    int n0 = blockIdx.y * 64;
    int kz = blockIdx.z;
    int tx = t & 15, ty = t >> 4;
    int ug = t >> 3, vg4 = (t & 7) * 4;   // A-gen: u-row ug, v-cols vg4..+3

    // stage s (8 per thread) + global max
    float4 sa = *(const float4*)&s[t * 8];
    float4 sb = *(const float4*)&s[t * 8 + 4];
    *(float4*)&Ss[t * 8] = sa;
    *(float4*)&Ss[t * 8 + 4] = sb;
    float lm = fmaxf(fmaxf(fmaxf(sa.x, sa.y), fmaxf(sa.z, sa.w)),
                     fmaxf(fmaxf(sb.x, sb.y), fmaxf(sb.z, sb.w)));
#pragma unroll
    for (int off = 1; off < 64; off <<= 1) lm = fmaxf(lm, __shfl_xor(lm, off));
    if ((t & 63) == 0) red[t >> 6] = lm;
    __syncthreads();
    float smax = fmaxf(red[0], red[1]);

    float4 dv = *(const float4*)&d[m0 + vg4];
    float4 mv = {leaky_f(smax + dv.x), leaky_f(smax + dv.y),
                 leaky_f(smax + dv.z), leaky_f(smax + dv.w)};
    float4 dsum = {0.f, 0.f, 0.f, 0.f};
    float acc[4][4] = {};

    for (int k0 = kz * CH; k0 < kz * CH + CH; k0 += 16) {
        float4 bv0 = *(const float4*)&h[(size_t)(k0 + ty) * D + n0 + tx * 4];
        float4 bv1 = *(const float4*)&h[(size_t)(k0 + 8 + ty) * D + n0 + tx * 4];
        float su = Ss[k0 + ug];
        float4 avv;
        avv.x = __expf(leaky_f(su + dv.x) - mv.x);
        avv.y = __expf(leaky_f(su + dv.y) - mv.y);
        avv.z = __expf(leaky_f(su + dv.z) - mv.z);
        avv.w = __expf(leaky_f(su + dv.w) - mv.w);
        dsum.x += avv.x; dsum.y += avv.y; dsum.z += avv.z; dsum.w += avv.w;
        __syncthreads();
        *(float4*)&As[ug][vg4] = avv;
        *(float4*)&Bs[ty][tx * 4] = bv0;
        *(float4*)&Bs[ty + 8][tx * 4] = bv1;
        __syncthreads();
#pragma unroll
        for (int kk = 0; kk < 16; ++kk) {
            float4 a4 = *(const float4*)&As[kk][ty * 4];
            float4 b4 = *(const float4*)&Bs[kk][tx * 4];
            float aa[4] = {a4.x, a4.y, a4.z, a4.w};
            float bb4[4] = {b4.x, b4.y, b4.z, b4.w};
#pragma unroll
            for (int i = 0; i < 4; ++i)
#pragma unroll
                for (int j = 0; j < 4; ++j)
                    acc[i][j] += aa[i] * bb4[j];
        }
    }

    __syncthreads();
    *(float4*)&part[ug][vg4] = dsum;
    __syncthreads();

#pragma unroll
    for (int i = 0; i < 4; ++i) {
        int r = ty * 4 + i;
        float4 o = {acc[i][0], acc[i][1], acc[i][2], acc[i][3]};
        *(float4*)&pacc[((size_t)kz * 1024 + m0 + r) * D + n0 + tx * 4] = o;
    }
    if (t < 32) {
        float den = 0.f;
#pragma unroll
        for (int u = 0; u < 16; ++u) den += part[u][t];
        pden[kz * 1024 + m0 + t] = den;   // redundant across n0-blocks: same value, benign
    }
}

// combine split-K partials: out[v,c] = relu(sum_ks pacc / sum_ks pden + bias)
template <int D, int KS>
__global__ void gat_combine(const float* __restrict__ pacc, const float* __restrict__ pden,
                            const float* __restrict__ bias, float* __restrict__ out)
{
    int idx = blockIdx.x * blockDim.x + threadIdx.x;
    if (idx >= 1024 * D / 4) return;
    int c4 = idx & (D / 4 - 1);
    int v = idx / (D / 4);
    float4 a = {0.f, 0.f, 0.f, 0.f};
    float den = 0.f;
#pragma unroll
    for (int ks = 0; ks < KS; ++ks) {
        float4 p = ((const float4*)pacc)[(size_t)(ks * 1024 + v) * (D / 4) + c4];
        a.x += p.x; a.y += p.y; a.z += p.z; a.w += p.w;
        den += pden[ks * 1024 + v];
    }
    float rd = 1.f / den;
    float4 bz = ((const float4*)bias)[c4];
    float4 o = {relu_f(a.x * rd + bz.x), relu_f(a.y * rd + bz.y),
                relu_f(a.z * rd + bz.z), relu_f(a.w * rd + bz.w)};
    ((float4*)out)[(size_t)v * (D / 4) + c4] = o;
}

// ---------------- self-loop-only rows v in [1024,8192): out = relu(h[v] + bias) ----------------
template <int D>
__global__ void gat_self4(const float* __restrict__ h, const float* __restrict__ bias,
                          float* __restrict__ out)
{
    int idx = blockIdx.x * blockDim.x + threadIdx.x;
    if (idx >= 7168 * D / 4) return;
    int c4 = idx & (D / 4 - 1);
    int n = 1024 + idx / (D / 4);
    float4 v = ((const float4*)h)[(size_t)n * (D / 4) + c4];
    float4 bz = ((const float4*)bias)[c4];
    float4 o = {relu_f(v.x + bz.x), relu_f(v.y + bz.y),
                relu_f(v.z + bz.z), relu_f(v.w + bz.w)};
    ((float4*)out)[(size_t)n * (D / 4) + c4] = o;
}

// ---------------- mean-pool stage 1: 128 blocks, each sums 64 rows ----------------
__global__ void pool_part(const float* __restrict__ x2, float* __restrict__ part)
{
    int b = blockIdx.x >> 4, seg = blockIdx.x & 15, t = threadIdx.x;
    const float* p = x2 + ((size_t)b * 1024 + seg * 64) * 128 + t;
    float acc = 0.f;
#pragma unroll 8
    for (int n = 0; n < 64; ++n) acc += p[(size_t)n * 128];
    part[(b * 16 + seg) * 128 + t] = acc;
}

// ---------------- head: reduce partials + linear + log_softmax ----------------
__global__ void head_kernel(const float* __restrict__ part, const float* __restrict__ ow,
                            const float* __restrict__ ob, float* __restrict__ out)
{
    __shared__ float pooled[128];
    __shared__ float logits[10];
    int b = blockIdx.x, t = threadIdx.x;
    float acc = 0.f;
#pragma unroll
    for (int sgi = 0; sgi < 16; ++sgi) acc += part[(b * 16 + sgi) * 128 + t];
    pooled[t] = acc * (1.f / 1024.f);
    __syncthreads();
    if (t < 10) {
        float l = ob[t];
        for (int c = 0; c < 128; ++c) l += pooled[c] * ow[c * 10 + t];
        logits[t] = l;
    }
    __syncthreads();
    if (t == 0) {
        float mx = logits[0];
        for (int j = 1; j < 10; ++j) mx = fmaxf(mx, logits[j]);
        float sum = 0.f;
        for (int j = 0; j < 10; ++j) sum += expf(logits[j] - mx);
        float lse = mx + logf(sum);
        for (int j = 0; j < 10; ++j) out[b * 10 + j] = logits[j] - lse;
    }
}

extern "C" void kernel_launch(void* const* d_in, const int* in_sizes, int n_in,
                              void* d_out, int out_size, void* d_ws, size_t ws_size,
                              hipStream_t stream)
{
    const float* images = (const float*)d_in[0];
    const float* c1w = (const float*)d_in[1];
    const float* c1b = (const float*)d_in[2];
    const float* bn1g = (const float*)d_in[3];
    const float* bn1b = (const float*)d_in[4];
    const float* bn1m = (const float*)d_in[5];
    const float* bn1v = (const float*)d_in[6];
    const float* c2w = (const float*)d_in[7];
    const float* c2b = (const float*)d_in[8];
    const float* bn2g = (const float*)d_in[9];
    const float* bn2b = (const float*)d_in[10];
    const float* bn2m = (const float*)d_in[11];
    const float* bn2v = (const float*)d_in[12];
    const float* g1w = (const float*)d_in[13];
    const float* g1as = (const float*)d_in[14];
    const float* g1ad = (const float*)d_in[15];
    const float* g1b = (const float*)d_in[16];
    const float* g2w = (const float*)d_in[17];
    const float* g2as = (const float*)d_in[18];
    const float* g2ad = (const float*)d_in[19];
    const float* g2b = (const float*)d_in[20];
    const float* ow = (const float*)d_in[21];
    const float* ob = (const float*)d_in[22];
    float* out = (float*)d_out;

    // ws layout (floats), total ~27.3 MB:
    // [x1 2097152][bufc1 524288][h1 2097152][x0 1048576][h2 1048576][s1,d1,s2,d2]
    // pacc1 (KS=8, 2M fl) aliases x0+h2 (both dead/unwritten during gat1-agg)
    // pacc2 (KS=16, 2M fl) aliases h1 (dead after gat_self1)
    // part/pden1/pden2 alias bufc1 (dead after conv2); x2 aliases x0 (dead after combine1)
    float* ws = (float*)d_ws;
    float* x1    = ws;                   // 2,097,152
    float* bufc1 = ws + 2097152;         //   524,288
    float* h1    = ws + 2621440;         // 2,097,152
    float* x0    = ws + 4718592;         // 1,048,576
    float* h2    = ws + 5767168;         // 1,048,576
    float* s1    = ws + 6815744;         // 1,024
    float* d1    = ws + 6816768;
    float* s2    = ws + 6817792;
    float* d2    = ws + 6818816;
    float* part  = bufc1;                // 16,384
    float* pden1 = bufc1 + 16384;        // 8,192
    float* pden2 = bufc1 + 24576;        // 16,384
    float* pacc1 = x0;                   // 8*1024*256 = 2,097,152 (spans x0+h2)
    float* pacc2 = h1;                   // 16*1024*128 = 2,097,152
    float* x2    = x0;

    conv1_pool<<<512, 256, 0, stream>>>(images, c1w, c1b, bn1g, bn1b, bn1m, bn1v, bufc1);
    conv2_fused<<<512, 256, 0, stream>>>(bufc1, c2w, c2b, bn2g, bn2b, bn2m, bn2v, x0);

    gemm32<128, 256><<<dim3(256, 4), 128, 0, stream>>>(x0, g1w, h1);
    score_kernel<<<256, 256, 0, stream>>>(h1, g1as, g1ad, s1, d1, 256, 1024);
    gat_agg_gemm<256, 8><<<dim3(32, 4, 8), 128, 0, stream>>>(h1, s1, d1, pacc1, pden1);
    gat_combine<256, 8><<<256, 256, 0, stream>>>(pacc1, pden1, g1b, x1);
    gat_self4<256><<<1792, 256, 0, stream>>>(h1, g1b, x1);

    gemm32<256, 128><<<dim3(256, 2), 128, 0, stream>>>(x1, g2w, h2);
    score_kernel<<<256, 256, 0, stream>>>(h2, g2as, g2ad, s2, d2, 128, 1024);
    gat_agg_gemm<128, 16><<<dim3(32, 2, 16), 128, 0, stream>>>(h2, s2, d2, pacc2, pden2);
    gat_combine<128, 16><<<128, 256, 0, stream>>>(pacc2, pden2, g2b, x2);
    gat_self4<128><<<896, 256, 0, stream>>>(h2, g2b, x2);

    pool_part<<<128, 128, 0, stream>>>(x2, part);
    head_kernel<<<8, 128, 0, stream>>>(part, ow, ob, out);
}